// Round 1
// baseline (1045.837 us; speedup 1.0000x reference)
//
#include <hip/hip_runtime.h>
#include <math.h>

#define N_NODES 16384
#define N_EDGES 262144
#define HDIM    128
#define NG50    50
#define NLAYER  6
#define NGRAPH  16
#define TROWS   2049
#define RMAXF   4.34f

__device__ __forceinline__ float ssp_f(float x){
  // shifted softplus: log1p(exp(x)) - ln2
  return (x > 20.0f ? x : log1pf(__expf(x))) - 0.6931471805599453f;
}
__device__ __forceinline__ void fma4(float4& c, float a, const float4 b){
  c.x = fmaf(a,b.x,c.x); c.y = fmaf(a,b.y,c.y); c.z = fmaf(a,b.z,c.z); c.w = fmaf(a,b.w,c.w);
}

// ---------------- h = emb[z] ----------------
__global__ __launch_bounds__(256) void k_init_h(const int* __restrict__ z,
    const float* __restrict__ emb, float* __restrict__ h){
  int t = blockIdx.x*256 + threadIdx.x;            // N*32 threads, float4 each
  int n = t >> 5, q = t & 31;
  ((float4*)h)[t] = ((const float4*)emb)[(z[n]<<5) + q];
}

// ---------------- edge distances (PBC minimum image) ----------------
__global__ __launch_bounds__(256) void k_geom(const int* __restrict__ ei,
    const float* __restrict__ pos, float* __restrict__ ew){
  int e = blockIdx.x*256 + threadIdx.x;
  if (e >= N_EDGES) return;
  int a = ei[e], b = ei[N_EDGES + e];
  float dx = pos[3*a+0] - pos[3*b+0];
  float dy = pos[3*a+1] - pos[3*b+1];
  float dz = pos[3*a+2] - pos[3*b+2];
  dx -= rintf(dx*0.2f)*5.0f;   // rintf = round-half-even, matches jnp.round
  dy -= rintf(dy*0.2f)*5.0f;
  dz -= rintf(dz*0.2f)*5.0f;
  ew[e] = sqrtf(fmaf(dx,dx,fmaf(dy,dy,dz*dz)));
}

// ---------------- per-layer filter tables: tab_l(r) = (ssp(ea(r)@w1+b1)@w2+b2)*C(r) ----------------
#define TAB_RPB 8
#define TAB_NB  257   // ceil(2049/8)
__global__ __launch_bounds__(128) void k_tab(const float* __restrict__ w1, const float* __restrict__ b1,
      const float* __restrict__ w2, const float* __restrict__ b2, float* __restrict__ tab){
  __shared__ float w1s[NG50*HDIM];
  __shared__ float sT[TAB_RPB*HDIM];
  int l  = blockIdx.x / TAB_NB;
  int i0 = (blockIdx.x % TAB_NB) * TAB_RPB;
  int j  = threadIdx.x;
  for (int i = j; i < NG50*HDIM; i += 128) w1s[i] = w1[l*NG50*HDIM + i];
  float b1v = b1[l*HDIM + j];
  float b2v = b2[l*HDIM + j];
  const float* w2l = w2 + (size_t)l*HDIM*HDIM;
  float* tabl = tab + (size_t)l*TROWS*HDIM;
  const float STEP = RMAXF/2048.0f;
  const float GS   = 10.0f/49.0f;          // gaussian offset spacing
  const float GC   = -0.5f/(GS*GS);        // coeff
  __syncthreads();
  for (int rr=0; rr<TAB_RPB; ++rr){
    int ri = i0 + rr; if (ri > TROWS-1) ri = TROWS-1;
    float r = ri*STEP;
    float acc = 0.f;
    for (int k=0;k<NG50;++k){
      float d = r - k*GS;
      acc = fmaf(__expf(GC*d*d), w1s[k*HDIM + j], acc);
    }
    sT[rr*HDIM + j] = ssp_f(acc + b1v);
  }
  __syncthreads();
  float o[TAB_RPB];
  #pragma unroll
  for (int rr=0;rr<TAB_RPB;++rr) o[rr]=0.f;
  for (int k=0;k<HDIM;++k){
    float wv = w2l[k*HDIM + j];
    #pragma unroll
    for (int rr=0;rr<TAB_RPB;++rr) o[rr] = fmaf(sT[rr*HDIM + k], wv, o[rr]);
  }
  for (int rr=0;rr<TAB_RPB;++rr){
    int ri = i0 + rr;
    if (ri < TROWS){
      float r = ri*STEP;
      float C = 0.5f*(cosf(r*0.31415926535897931f) + 1.0f);   // cosine cutoff (r < 10 always)
      tabl[ri*HDIM + j] = (o[rr] + b2v)*C;
    }
  }
}

// ---------------- CSR build (group edges by destination col) ----------------
__global__ __launch_bounds__(256) void k_hist(const int* __restrict__ ei, int* __restrict__ cursor){
  int e = blockIdx.x*256 + threadIdx.x;
  if (e < N_EDGES) atomicAdd(&cursor[ei[N_EDGES + e]], 1);
}
__global__ __launch_bounds__(1024) void k_scan(int* __restrict__ cursor, int* __restrict__ rowptr){
  __shared__ int sbuf[1024];
  int t = threadIdx.x;
  int base = t*16;
  int d[16]; int s = 0;
  #pragma unroll
  for (int i=0;i<16;++i){ d[i] = cursor[base+i]; s += d[i]; }
  sbuf[t] = s; __syncthreads();
  for (int off=1; off<1024; off<<=1){
    int v = sbuf[t];
    int add = (t >= off) ? sbuf[t-off] : 0;
    __syncthreads();
    sbuf[t] = v + add;
    __syncthreads();
  }
  int run = (t==0) ? 0 : sbuf[t-1];
  #pragma unroll
  for (int i=0;i<16;++i){ rowptr[base+i] = run; cursor[base+i] = run; run += d[i]; }
  if (t==1023) rowptr[N_NODES] = run;
}
__global__ __launch_bounds__(256) void k_fill(const int* __restrict__ ei, int* __restrict__ cursor,
    int* __restrict__ elist){
  int e = blockIdx.x*256 + threadIdx.x;
  if (e < N_EDGES){
    int c = ei[N_EDGES + e];
    int slot = atomicAdd(&cursor[c], 1);
    elist[slot] = e;
  }
}

// ---------------- xh = h @ cf_w1[l]   (16384x128 @ 128x128, fp32) ----------------
// 256 thr, 32-row tile, 4 rows x 4 cols per thread. A-loads are 2-address
// broadcasts (L1-hot), B-loads coalesced (L1/L2-hot). No LDS, no barriers.
__global__ __launch_bounds__(256,2) void k_gemm_xh(const float* __restrict__ A,
    const float* __restrict__ B, float* __restrict__ C){
  int tid = threadIdx.x;
  int m0 = blockIdx.x*32;
  int tc = tid & 31, tr = tid >> 5;
  int j0 = tc*4;
  const float* Arow = A + (size_t)(m0 + tr*4)*HDIM;
  float4 acc0 = make_float4(0,0,0,0), acc1 = acc0, acc2 = acc0, acc3 = acc0;
  #pragma unroll 2
  for (int k=0;k<HDIM;k+=4){
    float4 b0 = *(const float4*)(B + (k+0)*HDIM + j0);
    float4 b1 = *(const float4*)(B + (k+1)*HDIM + j0);
    float4 b2 = *(const float4*)(B + (k+2)*HDIM + j0);
    float4 b3 = *(const float4*)(B + (k+3)*HDIM + j0);
    float4 a0 = *(const float4*)(Arow + 0*HDIM + k);
    float4 a1 = *(const float4*)(Arow + 1*HDIM + k);
    float4 a2 = *(const float4*)(Arow + 2*HDIM + k);
    float4 a3 = *(const float4*)(Arow + 3*HDIM + k);
    fma4(acc0,a0.x,b0); fma4(acc0,a0.y,b1); fma4(acc0,a0.z,b2); fma4(acc0,a0.w,b3);
    fma4(acc1,a1.x,b0); fma4(acc1,a1.y,b1); fma4(acc1,a1.z,b2); fma4(acc1,a1.w,b3);
    fma4(acc2,a2.x,b0); fma4(acc2,a2.y,b1); fma4(acc2,a2.z,b2); fma4(acc2,a2.w,b3);
    fma4(acc3,a3.x,b0); fma4(acc3,a3.y,b1); fma4(acc3,a3.z,b2); fma4(acc3,a3.w,b3);
  }
  float* Crow = C + (size_t)(m0 + tr*4)*HDIM + j0;
  *(float4*)(Crow + 0*HDIM) = acc0;
  *(float4*)(Crow + 1*HDIM) = acc1;
  *(float4*)(Crow + 2*HDIM) = acc2;
  *(float4*)(Crow + 3*HDIM) = acc3;
}

// ---------------- edge aggregation: agg[c] = sum_e xh[row_e] * lerp(tab_l, ew_e) ----------------
// one wave per destination node, float2 per lane (64 lanes x 2 = 128 channels)
__global__ __launch_bounds__(256) void k_agg(const int* __restrict__ ei, const int* __restrict__ rowptr,
    const int* __restrict__ elist, const float* __restrict__ ew,
    const float* __restrict__ tabl, const float* __restrict__ xh, float* __restrict__ agg){
  int c = blockIdx.x*4 + (threadIdx.x >> 6);
  int lane = threadIdx.x & 63;
  int beg = rowptr[c], end = rowptr[c+1];
  const float INVSTEP = 2048.0f/RMAXF;
  float ax = 0.f, ay = 0.f;
  for (int k = beg; k < end; ++k){
    int e = elist[k];
    int rsrc = ei[e];
    float t = ew[e] * INVSTEP;
    int i0 = (int)t; if (i0 > 2047) i0 = 2047;
    float fr = t - (float)i0;
    float2 a = ((const float2*)(tabl + (size_t)i0*HDIM))[lane];
    float2 b = ((const float2*)(tabl + (size_t)(i0+1)*HDIM))[lane];
    float wx = fmaf(fr, b.x - a.x, a.x);
    float wy = fmaf(fr, b.y - a.y, a.y);
    float2 x = ((const float2*)(xh + (size_t)rsrc*HDIM))[lane];
    ax = fmaf(x.x, wx, ax);
    ay = fmaf(x.y, wy, ay);
  }
  float2 r; r.x = ax; r.y = ay;
  ((float2*)(agg + (size_t)c*HDIM))[lane] = r;
}

// ---------------- fused: h += ssp(agg@cf_w2 + cf_b2) @ lin_w + lin_b ----------------
__global__ __launch_bounds__(256,2) void k_fused23(const float* __restrict__ Ain,
    const float* __restrict__ W2, const float* __restrict__ B2,
    const float* __restrict__ WL, const float* __restrict__ BL, float* __restrict__ Hio){
  __shared__ float Ss[32*HDIM];   // 16 KB
  int tid = threadIdx.x;
  int m0 = blockIdx.x*32;
  int tc = tid & 31, tr = tid >> 5;
  int j0 = tc*4;
  float4 acc0 = make_float4(0,0,0,0), acc1 = acc0, acc2 = acc0, acc3 = acc0;
  {
    const float* Arow = Ain + (size_t)(m0 + tr*4)*HDIM;
    #pragma unroll 2
    for (int k=0;k<HDIM;k+=4){
      float4 b0 = *(const float4*)(W2 + (k+0)*HDIM + j0);
      float4 b1 = *(const float4*)(W2 + (k+1)*HDIM + j0);
      float4 b2 = *(const float4*)(W2 + (k+2)*HDIM + j0);
      float4 b3 = *(const float4*)(W2 + (k+3)*HDIM + j0);
      float4 a0 = *(const float4*)(Arow + 0*HDIM + k);
      float4 a1 = *(const float4*)(Arow + 1*HDIM + k);
      float4 a2 = *(const float4*)(Arow + 2*HDIM + k);
      float4 a3 = *(const float4*)(Arow + 3*HDIM + k);
      fma4(acc0,a0.x,b0); fma4(acc0,a0.y,b1); fma4(acc0,a0.z,b2); fma4(acc0,a0.w,b3);
      fma4(acc1,a1.x,b0); fma4(acc1,a1.y,b1); fma4(acc1,a1.z,b2); fma4(acc1,a1.w,b3);
      fma4(acc2,a2.x,b0); fma4(acc2,a2.y,b1); fma4(acc2,a2.z,b2); fma4(acc2,a2.w,b3);
      fma4(acc3,a3.x,b0); fma4(acc3,a3.y,b1); fma4(acc3,a3.z,b2); fma4(acc3,a3.w,b3);
    }
  }
  float4 b2v = *(const float4*)(B2 + j0);
  {
    float* sr = Ss + (tr*4)*HDIM + j0;
    float4 v;
    v.x=ssp_f(acc0.x+b2v.x); v.y=ssp_f(acc0.y+b2v.y); v.z=ssp_f(acc0.z+b2v.z); v.w=ssp_f(acc0.w+b2v.w);
    *(float4*)(sr + 0*HDIM) = v;
    v.x=ssp_f(acc1.x+b2v.x); v.y=ssp_f(acc1.y+b2v.y); v.z=ssp_f(acc1.z+b2v.z); v.w=ssp_f(acc1.w+b2v.w);
    *(float4*)(sr + 1*HDIM) = v;
    v.x=ssp_f(acc2.x+b2v.x); v.y=ssp_f(acc2.y+b2v.y); v.z=ssp_f(acc2.z+b2v.z); v.w=ssp_f(acc2.w+b2v.w);
    *(float4*)(sr + 2*HDIM) = v;
    v.x=ssp_f(acc3.x+b2v.x); v.y=ssp_f(acc3.y+b2v.y); v.z=ssp_f(acc3.z+b2v.z); v.w=ssp_f(acc3.w+b2v.w);
    *(float4*)(sr + 3*HDIM) = v;
  }
  __syncthreads();
  acc0 = make_float4(0,0,0,0); acc1 = acc0; acc2 = acc0; acc3 = acc0;
  {
    const float* Srow = Ss + (tr*4)*HDIM;
    #pragma unroll 2
    for (int k=0;k<HDIM;k+=4){
      float4 b0 = *(const float4*)(WL + (k+0)*HDIM + j0);
      float4 b1 = *(const float4*)(WL + (k+1)*HDIM + j0);
      float4 b2 = *(const float4*)(WL + (k+2)*HDIM + j0);
      float4 b3 = *(const float4*)(WL + (k+3)*HDIM + j0);
      float4 a0 = *(const float4*)(Srow + 0*HDIM + k);
      float4 a1 = *(const float4*)(Srow + 1*HDIM + k);
      float4 a2 = *(const float4*)(Srow + 2*HDIM + k);
      float4 a3 = *(const float4*)(Srow + 3*HDIM + k);
      fma4(acc0,a0.x,b0); fma4(acc0,a0.y,b1); fma4(acc0,a0.z,b2); fma4(acc0,a0.w,b3);
      fma4(acc1,a1.x,b0); fma4(acc1,a1.y,b1); fma4(acc1,a1.z,b2); fma4(acc1,a1.w,b3);
      fma4(acc2,a2.x,b0); fma4(acc2,a2.y,b1); fma4(acc2,a2.z,b2); fma4(acc2,a2.w,b3);
      fma4(acc3,a3.x,b0); fma4(acc3,a3.y,b1); fma4(acc3,a3.z,b2); fma4(acc3,a3.w,b3);
    }
  }
  float4 blv = *(const float4*)(BL + j0);
  float* Hrow = Hio + (size_t)(m0 + tr*4)*HDIM + j0;
  {
    float4 hv;
    hv = *(float4*)(Hrow + 0*HDIM);
    hv.x += acc0.x+blv.x; hv.y += acc0.y+blv.y; hv.z += acc0.z+blv.z; hv.w += acc0.w+blv.w;
    *(float4*)(Hrow + 0*HDIM) = hv;
    hv = *(float4*)(Hrow + 1*HDIM);
    hv.x += acc1.x+blv.x; hv.y += acc1.y+blv.y; hv.z += acc1.z+blv.z; hv.w += acc1.w+blv.w;
    *(float4*)(Hrow + 1*HDIM) = hv;
    hv = *(float4*)(Hrow + 2*HDIM);
    hv.x += acc2.x+blv.x; hv.y += acc2.y+blv.y; hv.z += acc2.z+blv.z; hv.w += acc2.w+blv.w;
    *(float4*)(Hrow + 2*HDIM) = hv;
    hv = *(float4*)(Hrow + 3*HDIM);
    hv.x += acc3.x+blv.x; hv.y += acc3.y+blv.y; hv.z += acc3.z+blv.z; hv.w += acc3.w+blv.w;
    *(float4*)(Hrow + 3*HDIM) = hv;
  }
}

// ---------------- output MLP + graph readout ----------------
__global__ __launch_bounds__(256) void k_out(const float* __restrict__ h, const float* __restrict__ w1,
    const float* __restrict__ b1, const float* __restrict__ w2, const float* __restrict__ b2,
    const int* __restrict__ batch, float* __restrict__ gsum){
  int node = blockIdx.x*4 + (threadIdx.x >> 6);
  int lane = threadIdx.x & 63;
  float acc = b1[lane];
  const float* hrow = h + (size_t)node*HDIM;
  #pragma unroll 4
  for (int k=0;k<HDIM;++k) acc = fmaf(hrow[k], w1[k*64 + lane], acc);
  float s = ssp_f(acc) * w2[lane];
  for (int off=32; off>0; off>>=1) s += __shfl_down(s, off, 64);
  if (lane == 0) atomicAdd(&gsum[batch[node]], s + b2[0]);
}

__global__ void k_sigmoid(const float* __restrict__ gsum, float* __restrict__ out){
  int t = threadIdx.x;
  if (t < NGRAPH) out[t] = 1.0f/(1.0f + __expf(-gsum[t]));
}

// ---------------- host ----------------
extern "C" void kernel_launch(void* const* d_in, const int* in_sizes, int n_in,
                              void* d_out, int out_size, void* d_ws, size_t ws_size,
                              hipStream_t stream){
  (void)in_sizes; (void)n_in; (void)out_size;
  const int*   z      = (const int*)  d_in[0];
  const float* pos    = (const float*)d_in[1];
  const int*   ei     = (const int*)  d_in[2];
  const int*   batch  = (const int*)  d_in[3];
  const float* emb    = (const float*)d_in[4];
  const float* mlp_w1 = (const float*)d_in[5];
  const float* mlp_b1 = (const float*)d_in[6];
  const float* mlp_w2 = (const float*)d_in[7];
  const float* mlp_b2 = (const float*)d_in[8];
  const float* cf_w1  = (const float*)d_in[9];
  const float* cf_w2  = (const float*)d_in[10];
  const float* cf_b2  = (const float*)d_in[11];
  const float* lin_w  = (const float*)d_in[12];
  const float* lin_b  = (const float*)d_in[13];
  const float* ow1    = (const float*)d_in[14];
  const float* ob1    = (const float*)d_in[15];
  const float* ow2    = (const float*)d_in[16];
  const float* ob2    = (const float*)d_in[17];

  char* wp = (char*)d_ws;
  size_t used = 0;
  auto alloc = [&](size_t bytes)->char*{
    char* p = wp + used;
    used += (bytes + 1023) & ~(size_t)1023;
    return p;
  };
  float* ew     = (float*)alloc((size_t)N_EDGES*4);
  float* tab    = (float*)alloc((size_t)NLAYER*TROWS*HDIM*4);
  float* h      = (float*)alloc((size_t)N_NODES*HDIM*4);
  float* xh     = (float*)alloc((size_t)N_NODES*HDIM*4);
  float* agg    = (float*)alloc((size_t)N_NODES*HDIM*4);
  int*   rowptr = (int*)  alloc((size_t)(N_NODES+1)*4);
  int*   cursor = (int*)  alloc((size_t)N_NODES*4);
  int*   elist  = (int*)  alloc((size_t)N_EDGES*4);
  float* gsum   = (float*)alloc((size_t)NGRAPH*4);
  if (used > ws_size) return;  // workspace too small -> visible failure

  hipMemsetAsync(cursor, 0, (size_t)N_NODES*4, stream);
  hipMemsetAsync(gsum, 0, (size_t)NGRAPH*4, stream);

  k_init_h<<<N_NODES*32/256, 256, 0, stream>>>(z, emb, h);
  k_geom  <<<N_EDGES/256, 256, 0, stream>>>(ei, pos, ew);
  k_tab   <<<NLAYER*TAB_NB, 128, 0, stream>>>(mlp_w1, mlp_b1, mlp_w2, mlp_b2, tab);
  k_hist  <<<N_EDGES/256, 256, 0, stream>>>(ei, cursor);
  k_scan  <<<1, 1024, 0, stream>>>(cursor, rowptr);
  k_fill  <<<N_EDGES/256, 256, 0, stream>>>(ei, cursor, elist);

  for (int l=0; l<NLAYER; ++l){
    k_gemm_xh<<<N_NODES/32, 256, 0, stream>>>(h, cf_w1 + (size_t)l*HDIM*HDIM, xh);
    k_agg    <<<N_NODES/4, 256, 0, stream>>>(ei, rowptr, elist, ew,
                 tab + (size_t)l*TROWS*HDIM, xh, agg);
    k_fused23<<<N_NODES/32, 256, 0, stream>>>(agg,
                 cf_w2 + (size_t)l*HDIM*HDIM, cf_b2 + (size_t)l*HDIM,
                 lin_w + (size_t)l*HDIM*HDIM, lin_b + (size_t)l*HDIM, h);
  }
  k_out    <<<N_NODES/4, 256, 0, stream>>>(h, ow1, ob1, ow2, ob2, batch, gsum);
  k_sigmoid<<<1, 64, 0, stream>>>(gsum, (float*)d_out);
}

// Round 2
// 722.491 us; speedup vs baseline: 1.4475x; 1.4475x over previous
//
#include <hip/hip_runtime.h>
#include <math.h>

#define N_NODES 16384
#define N_EDGES 262144
#define HDIM    128
#define NG50    50
#define NLAYER  6
#define NGRAPH  16
#define TROWS   2049
#define RMAXF   4.34f

__device__ __forceinline__ float ssp_f(float x){
  return (x > 20.0f ? x : log1pf(__expf(x))) - 0.6931471805599453f;
}
__device__ __forceinline__ void fma4(float4& c, float a, const float4 b){
  c.x = fmaf(a,b.x,c.x); c.y = fmaf(a,b.y,c.y); c.z = fmaf(a,b.z,c.z); c.w = fmaf(a,b.w,c.w);
}

// ---------------- h = emb[z] ----------------
__global__ __launch_bounds__(256) void k_init_h(const int* __restrict__ z,
    const float* __restrict__ emb, float* __restrict__ h){
  int t = blockIdx.x*256 + threadIdx.x;
  int n = t >> 5, q = t & 31;
  ((float4*)h)[t] = ((const float4*)emb)[(z[n]<<5) + q];
}

// ---------------- edge distances (PBC minimum image), stored pre-scaled t = r*2048/RMAX ----------------
__global__ __launch_bounds__(256) void k_geom(const int* __restrict__ ei,
    const float* __restrict__ pos, float* __restrict__ tsc){
  int e = blockIdx.x*256 + threadIdx.x;
  if (e >= N_EDGES) return;
  int a = ei[e], b = ei[N_EDGES + e];
  float dx = pos[3*a+0] - pos[3*b+0];
  float dy = pos[3*a+1] - pos[3*b+1];
  float dz = pos[3*a+2] - pos[3*b+2];
  dx -= rintf(dx*0.2f)*5.0f;
  dy -= rintf(dy*0.2f)*5.0f;
  dz -= rintf(dz*0.2f)*5.0f;
  float r = sqrtf(fmaf(dx,dx,fmaf(dy,dy,dz*dz)));
  tsc[e] = r * (2048.0f/RMAXF);
}

// ---------------- per-layer filter tables ----------------
#define TAB_RPB 8
#define TAB_NB  257
__global__ __launch_bounds__(128) void k_tab(const float* __restrict__ w1, const float* __restrict__ b1,
      const float* __restrict__ w2, const float* __restrict__ b2, float* __restrict__ tab){
  __shared__ float w1s[NG50*HDIM];
  __shared__ float sT[TAB_RPB*HDIM];
  int l  = blockIdx.x / TAB_NB;
  int i0 = (blockIdx.x % TAB_NB) * TAB_RPB;
  int j  = threadIdx.x;
  for (int i = j; i < NG50*HDIM; i += 128) w1s[i] = w1[l*NG50*HDIM + i];
  float b1v = b1[l*HDIM + j];
  float b2v = b2[l*HDIM + j];
  const float* w2l = w2 + (size_t)l*HDIM*HDIM;
  float* tabl = tab + (size_t)l*TROWS*HDIM;
  const float STEP = RMAXF/2048.0f;
  const float GS   = 10.0f/49.0f;
  const float GC   = -0.5f/(GS*GS);
  __syncthreads();
  for (int rr=0; rr<TAB_RPB; ++rr){
    int ri = i0 + rr; if (ri > TROWS-1) ri = TROWS-1;
    float r = ri*STEP;
    float acc = 0.f;
    for (int k=0;k<NG50;++k){
      float d = r - k*GS;
      acc = fmaf(__expf(GC*d*d), w1s[k*HDIM + j], acc);
    }
    sT[rr*HDIM + j] = ssp_f(acc + b1v);
  }
  __syncthreads();
  float o[TAB_RPB];
  #pragma unroll
  for (int rr=0;rr<TAB_RPB;++rr) o[rr]=0.f;
  for (int k=0;k<HDIM;++k){
    float wv = w2l[k*HDIM + j];
    #pragma unroll
    for (int rr=0;rr<TAB_RPB;++rr) o[rr] = fmaf(sT[rr*HDIM + k], wv, o[rr]);
  }
  for (int rr=0;rr<TAB_RPB;++rr){
    int ri = i0 + rr;
    if (ri < TROWS){
      float r = ri*STEP;
      float C = 0.5f*(cosf(r*0.31415926535897931f) + 1.0f);
      tabl[ri*HDIM + j] = (o[rr] + b2v)*C;
    }
  }
}

// ---------------- CSR build (dst-grouped), with per-slot (src, t) records ----------------
__global__ __launch_bounds__(256) void k_hist(const int* __restrict__ ei, int* __restrict__ cursor){
  int e = blockIdx.x*256 + threadIdx.x;
  if (e < N_EDGES) atomicAdd(&cursor[ei[N_EDGES + e]], 1);
}
__global__ __launch_bounds__(1024) void k_scan(int* __restrict__ cursor, int* __restrict__ rowptr){
  __shared__ int sbuf[1024];
  int t = threadIdx.x;
  int base = t*16;
  int d[16]; int s = 0;
  #pragma unroll
  for (int i=0;i<16;++i){ d[i] = cursor[base+i]; s += d[i]; }
  sbuf[t] = s; __syncthreads();
  for (int off=1; off<1024; off<<=1){
    int v = sbuf[t];
    int add = (t >= off) ? sbuf[t-off] : 0;
    __syncthreads();
    sbuf[t] = v + add;
    __syncthreads();
  }
  int run = (t==0) ? 0 : sbuf[t-1];
  #pragma unroll
  for (int i=0;i<16;++i){ rowptr[base+i] = run; cursor[base+i] = run; run += d[i]; }
  if (t==1023) rowptr[N_NODES] = run;
}
__global__ __launch_bounds__(256) void k_fill(const int* __restrict__ ei, const float* __restrict__ tsc,
    int* __restrict__ cursor, int* __restrict__ srcl, float* __restrict__ tl){
  int e = blockIdx.x*256 + threadIdx.x;
  if (e < N_EDGES){
    int c = ei[N_EDGES + e];
    int slot = atomicAdd(&cursor[c], 1);
    srcl[slot] = ei[e];
    tl[slot]   = tsc[e];
  }
}

// ---------------- xh = h @ cf_w1[l] ----------------
__global__ __launch_bounds__(256,2) void k_gemm_xh(const float* __restrict__ A,
    const float* __restrict__ B, float* __restrict__ C){
  int tid = threadIdx.x;
  int m0 = blockIdx.x*32;
  int tc = tid & 31, tr = tid >> 5;
  int j0 = tc*4;
  const float* Arow = A + (size_t)(m0 + tr*4)*HDIM;
  float4 acc0 = make_float4(0,0,0,0), acc1 = acc0, acc2 = acc0, acc3 = acc0;
  #pragma unroll 2
  for (int k=0;k<HDIM;k+=4){
    float4 b0 = *(const float4*)(B + (k+0)*HDIM + j0);
    float4 b1 = *(const float4*)(B + (k+1)*HDIM + j0);
    float4 b2 = *(const float4*)(B + (k+2)*HDIM + j0);
    float4 b3 = *(const float4*)(B + (k+3)*HDIM + j0);
    float4 a0 = *(const float4*)(Arow + 0*HDIM + k);
    float4 a1 = *(const float4*)(Arow + 1*HDIM + k);
    float4 a2 = *(const float4*)(Arow + 2*HDIM + k);
    float4 a3 = *(const float4*)(Arow + 3*HDIM + k);
    fma4(acc0,a0.x,b0); fma4(acc0,a0.y,b1); fma4(acc0,a0.z,b2); fma4(acc0,a0.w,b3);
    fma4(acc1,a1.x,b0); fma4(acc1,a1.y,b1); fma4(acc1,a1.z,b2); fma4(acc1,a1.w,b3);
    fma4(acc2,a2.x,b0); fma4(acc2,a2.y,b1); fma4(acc2,a2.z,b2); fma4(acc2,a2.w,b3);
    fma4(acc3,a3.x,b0); fma4(acc3,a3.y,b1); fma4(acc3,a3.z,b2); fma4(acc3,a3.w,b3);
  }
  float* Crow = C + (size_t)(m0 + tr*4)*HDIM + j0;
  *(float4*)(Crow + 0*HDIM) = acc0;
  *(float4*)(Crow + 1*HDIM) = acc1;
  *(float4*)(Crow + 2*HDIM) = acc2;
  *(float4*)(Crow + 3*HDIM) = acc3;
}

// ---------------- edge aggregation: one wave per dst node ----------------
// chunked: one coalesced (src,t) load per 64 edges, shfl-broadcast per edge,
// 2-edge manual unroll so both edges' vector loads are in flight together.
__global__ __launch_bounds__(256) void k_agg(const int* __restrict__ rowptr,
    const int* __restrict__ srcl, const float* __restrict__ tl,
    const float* __restrict__ tabl, const float* __restrict__ xh, float* __restrict__ agg){
  int c = blockIdx.x*4 + (threadIdx.x >> 6);
  int lane = threadIdx.x & 63;
  int beg = rowptr[c], end = rowptr[c+1];
  float ax = 0.f, ay = 0.f;
  for (int k0 = beg; k0 < end; k0 += 64){
    int rem = end - k0;
    int cnt = rem < 64 ? rem : 64;
    int   s_l = 0; float t_l = 0.f;
    if (lane < cnt){ s_l = srcl[k0+lane]; t_l = tl[k0+lane]; }
    int j = 0;
    for (; j+1 < cnt; j += 2){
      int   r0 = __shfl(s_l, j,   64);
      float t0 = __shfl(t_l, j,   64);
      int   r1 = __shfl(s_l, j+1, 64);
      float t1 = __shfl(t_l, j+1, 64);
      int i00 = (int)t0; if (i00 > 2047) i00 = 2047;
      int i01 = (int)t1; if (i01 > 2047) i01 = 2047;
      float f0 = t0 - (float)i00;
      float f1 = t1 - (float)i01;
      float2 a0 = ((const float2*)(tabl + (size_t)i00*HDIM))[lane];
      float2 b0 = ((const float2*)(tabl + (size_t)i00*HDIM + HDIM))[lane];
      float2 x0 = ((const float2*)(xh + (size_t)r0*HDIM))[lane];
      float2 a1 = ((const float2*)(tabl + (size_t)i01*HDIM))[lane];
      float2 b1 = ((const float2*)(tabl + (size_t)i01*HDIM + HDIM))[lane];
      float2 x1 = ((const float2*)(xh + (size_t)r1*HDIM))[lane];
      ax = fmaf(x0.x, fmaf(f0, b0.x-a0.x, a0.x), ax);
      ay = fmaf(x0.y, fmaf(f0, b0.y-a0.y, a0.y), ay);
      ax = fmaf(x1.x, fmaf(f1, b1.x-a1.x, a1.x), ax);
      ay = fmaf(x1.y, fmaf(f1, b1.y-a1.y, a1.y), ay);
    }
    if (j < cnt){
      int   r0 = __shfl(s_l, j, 64);
      float t0 = __shfl(t_l, j, 64);
      int i00 = (int)t0; if (i00 > 2047) i00 = 2047;
      float f0 = t0 - (float)i00;
      float2 a0 = ((const float2*)(tabl + (size_t)i00*HDIM))[lane];
      float2 b0 = ((const float2*)(tabl + (size_t)i00*HDIM + HDIM))[lane];
      float2 x0 = ((const float2*)(xh + (size_t)r0*HDIM))[lane];
      ax = fmaf(x0.x, fmaf(f0, b0.x-a0.x, a0.x), ax);
      ay = fmaf(x0.y, fmaf(f0, b0.y-a0.y, a0.y), ay);
    }
  }
  ((float2*)(agg + (size_t)c*HDIM))[lane] = make_float2(ax, ay);
}

// ---------------- fused: h += ssp(agg@cf_w2 + cf_b2) @ lin_w + lin_b ----------------
__global__ __launch_bounds__(256,2) void k_fused23(const float* __restrict__ Ain,
    const float* __restrict__ W2, const float* __restrict__ B2,
    const float* __restrict__ WL, const float* __restrict__ BL, float* __restrict__ Hio){
  __shared__ float Ss[32*HDIM];
  int tid = threadIdx.x;
  int m0 = blockIdx.x*32;
  int tc = tid & 31, tr = tid >> 5;
  int j0 = tc*4;
  float4 acc0 = make_float4(0,0,0,0), acc1 = acc0, acc2 = acc0, acc3 = acc0;
  {
    const float* Arow = Ain + (size_t)(m0 + tr*4)*HDIM;
    #pragma unroll 2
    for (int k=0;k<HDIM;k+=4){
      float4 b0 = *(const float4*)(W2 + (k+0)*HDIM + j0);
      float4 b1 = *(const float4*)(W2 + (k+1)*HDIM + j0);
      float4 b2 = *(const float4*)(W2 + (k+2)*HDIM + j0);
      float4 b3 = *(const float4*)(W2 + (k+3)*HDIM + j0);
      float4 a0 = *(const float4*)(Arow + 0*HDIM + k);
      float4 a1 = *(const float4*)(Arow + 1*HDIM + k);
      float4 a2 = *(const float4*)(Arow + 2*HDIM + k);
      float4 a3 = *(const float4*)(Arow + 3*HDIM + k);
      fma4(acc0,a0.x,b0); fma4(acc0,a0.y,b1); fma4(acc0,a0.z,b2); fma4(acc0,a0.w,b3);
      fma4(acc1,a1.x,b0); fma4(acc1,a1.y,b1); fma4(acc1,a1.z,b2); fma4(acc1,a1.w,b3);
      fma4(acc2,a2.x,b0); fma4(acc2,a2.y,b1); fma4(acc2,a2.z,b2); fma4(acc2,a2.w,b3);
      fma4(acc3,a3.x,b0); fma4(acc3,a3.y,b1); fma4(acc3,a3.z,b2); fma4(acc3,a3.w,b3);
    }
  }
  float4 b2v = *(const float4*)(B2 + j0);
  {
    float* sr = Ss + (tr*4)*HDIM + j0;
    float4 v;
    v.x=ssp_f(acc0.x+b2v.x); v.y=ssp_f(acc0.y+b2v.y); v.z=ssp_f(acc0.z+b2v.z); v.w=ssp_f(acc0.w+b2v.w);
    *(float4*)(sr + 0*HDIM) = v;
    v.x=ssp_f(acc1.x+b2v.x); v.y=ssp_f(acc1.y+b2v.y); v.z=ssp_f(acc1.z+b2v.z); v.w=ssp_f(acc1.w+b2v.w);
    *(float4*)(sr + 1*HDIM) = v;
    v.x=ssp_f(acc2.x+b2v.x); v.y=ssp_f(acc2.y+b2v.y); v.z=ssp_f(acc2.z+b2v.z); v.w=ssp_f(acc2.w+b2v.w);
    *(float4*)(sr + 2*HDIM) = v;
    v.x=ssp_f(acc3.x+b2v.x); v.y=ssp_f(acc3.y+b2v.y); v.z=ssp_f(acc3.z+b2v.z); v.w=ssp_f(acc3.w+b2v.w);
    *(float4*)(sr + 3*HDIM) = v;
  }
  __syncthreads();
  acc0 = make_float4(0,0,0,0); acc1 = acc0; acc2 = acc0; acc3 = acc0;
  {
    const float* Srow = Ss + (tr*4)*HDIM;
    #pragma unroll 2
    for (int k=0;k<HDIM;k+=4){
      float4 b0 = *(const float4*)(WL + (k+0)*HDIM + j0);
      float4 b1 = *(const float4*)(WL + (k+1)*HDIM + j0);
      float4 b2 = *(const float4*)(WL + (k+2)*HDIM + j0);
      float4 b3 = *(const float4*)(WL + (k+3)*HDIM + j0);
      float4 a0 = *(const float4*)(Srow + 0*HDIM + k);
      float4 a1 = *(const float4*)(Srow + 1*HDIM + k);
      float4 a2 = *(const float4*)(Srow + 2*HDIM + k);
      float4 a3 = *(const float4*)(Srow + 3*HDIM + k);
      fma4(acc0,a0.x,b0); fma4(acc0,a0.y,b1); fma4(acc0,a0.z,b2); fma4(acc0,a0.w,b3);
      fma4(acc1,a1.x,b0); fma4(acc1,a1.y,b1); fma4(acc1,a1.z,b2); fma4(acc1,a1.w,b3);
      fma4(acc2,a2.x,b0); fma4(acc2,a2.y,b1); fma4(acc2,a2.z,b2); fma4(acc2,a2.w,b3);
      fma4(acc3,a3.x,b0); fma4(acc3,a3.y,b1); fma4(acc3,a3.z,b2); fma4(acc3,a3.w,b3);
    }
  }
  float4 blv = *(const float4*)(BL + j0);
  float* Hrow = Hio + (size_t)(m0 + tr*4)*HDIM + j0;
  {
    float4 hv;
    hv = *(float4*)(Hrow + 0*HDIM);
    hv.x += acc0.x+blv.x; hv.y += acc0.y+blv.y; hv.z += acc0.z+blv.z; hv.w += acc0.w+blv.w;
    *(float4*)(Hrow + 0*HDIM) = hv;
    hv = *(float4*)(Hrow + 1*HDIM);
    hv.x += acc1.x+blv.x; hv.y += acc1.y+blv.y; hv.z += acc1.z+blv.z; hv.w += acc1.w+blv.w;
    *(float4*)(Hrow + 1*HDIM) = hv;
    hv = *(float4*)(Hrow + 2*HDIM);
    hv.x += acc2.x+blv.x; hv.y += acc2.y+blv.y; hv.z += acc2.z+blv.z; hv.w += acc2.w+blv.w;
    *(float4*)(Hrow + 2*HDIM) = hv;
    hv = *(float4*)(Hrow + 3*HDIM);
    hv.x += acc3.x+blv.x; hv.y += acc3.y+blv.y; hv.z += acc3.z+blv.z; hv.w += acc3.w+blv.w;
    *(float4*)(Hrow + 3*HDIM) = hv;
  }
}

// ---------------- output MLP: per-node scalar (NO atomics) ----------------
__global__ __launch_bounds__(256) void k_outA(const float* __restrict__ h, const float* __restrict__ w1,
    const float* __restrict__ b1, const float* __restrict__ w2, const float* __restrict__ b2,
    float* __restrict__ nodeval){
  int node = blockIdx.x*4 + (threadIdx.x >> 6);
  int lane = threadIdx.x & 63;
  float acc = b1[lane];
  const float* hrow = h + (size_t)node*HDIM;
  #pragma unroll 4
  for (int k=0;k<HDIM;++k) acc = fmaf(hrow[k], w1[k*64 + lane], acc);
  float s = ssp_f(acc) * w2[lane];
  for (int off=32; off>0; off>>=1) s += __shfl_down(s, off, 64);
  if (lane == 0) nodeval[node] = s + b2[0];
}

// ---------------- graph readout: one block per graph, scan all nodes ----------------
__global__ __launch_bounds__(256) void k_outB(const float* __restrict__ nodeval,
    const int* __restrict__ batch, float* __restrict__ out){
  __shared__ float sred[4];
  int g = blockIdx.x;
  int t = threadIdx.x;
  float s = 0.f;
  for (int n = t; n < N_NODES; n += 256)
    if (batch[n] == g) s += nodeval[n];
  for (int off=32; off>0; off>>=1) s += __shfl_down(s, off, 64);
  if ((t & 63) == 0) sred[t >> 6] = s;
  __syncthreads();
  if (t == 0){
    float tot = sred[0] + sred[1] + sred[2] + sred[3];
    out[g] = 1.0f/(1.0f + __expf(-tot));
  }
}

// ---------------- host ----------------
extern "C" void kernel_launch(void* const* d_in, const int* in_sizes, int n_in,
                              void* d_out, int out_size, void* d_ws, size_t ws_size,
                              hipStream_t stream){
  (void)in_sizes; (void)n_in; (void)out_size;
  const int*   z      = (const int*)  d_in[0];
  const float* pos    = (const float*)d_in[1];
  const int*   ei     = (const int*)  d_in[2];
  const int*   batch  = (const int*)  d_in[3];
  const float* emb    = (const float*)d_in[4];
  const float* mlp_w1 = (const float*)d_in[5];
  const float* mlp_b1 = (const float*)d_in[6];
  const float* mlp_w2 = (const float*)d_in[7];
  const float* mlp_b2 = (const float*)d_in[8];
  const float* cf_w1  = (const float*)d_in[9];
  const float* cf_w2  = (const float*)d_in[10];
  const float* cf_b2  = (const float*)d_in[11];
  const float* lin_w  = (const float*)d_in[12];
  const float* lin_b  = (const float*)d_in[13];
  const float* ow1    = (const float*)d_in[14];
  const float* ob1    = (const float*)d_in[15];
  const float* ow2    = (const float*)d_in[16];
  const float* ob2    = (const float*)d_in[17];

  char* wp = (char*)d_ws;
  size_t used = 0;
  auto alloc = [&](size_t bytes)->char*{
    char* p = wp + used;
    used += (bytes + 1023) & ~(size_t)1023;
    return p;
  };
  float* tsc     = (float*)alloc((size_t)N_EDGES*4);
  float* tab     = (float*)alloc((size_t)NLAYER*TROWS*HDIM*4);
  float* h       = (float*)alloc((size_t)N_NODES*HDIM*4);
  float* xh      = (float*)alloc((size_t)N_NODES*HDIM*4);
  float* agg     = (float*)alloc((size_t)N_NODES*HDIM*4);
  int*   rowptr  = (int*)  alloc((size_t)(N_NODES+1)*4);
  int*   cursor  = (int*)  alloc((size_t)N_NODES*4);
  int*   srcl    = (int*)  alloc((size_t)N_EDGES*4);
  float* tl      = (float*)alloc((size_t)N_EDGES*4);
  float* nodeval = (float*)alloc((size_t)N_NODES*4);
  if (used > ws_size) return;

  hipMemsetAsync(cursor, 0, (size_t)N_NODES*4, stream);

  k_init_h<<<N_NODES*32/256, 256, 0, stream>>>(z, emb, h);
  k_geom  <<<N_EDGES/256, 256, 0, stream>>>(ei, pos, tsc);
  k_tab   <<<NLAYER*TAB_NB, 128, 0, stream>>>(mlp_w1, mlp_b1, mlp_w2, mlp_b2, tab);
  k_hist  <<<N_EDGES/256, 256, 0, stream>>>(ei, cursor);
  k_scan  <<<1, 1024, 0, stream>>>(cursor, rowptr);
  k_fill  <<<N_EDGES/256, 256, 0, stream>>>(ei, tsc, cursor, srcl, tl);

  for (int l=0; l<NLAYER; ++l){
    k_gemm_xh<<<N_NODES/32, 256, 0, stream>>>(h, cf_w1 + (size_t)l*HDIM*HDIM, xh);
    k_agg    <<<N_NODES/4, 256, 0, stream>>>(rowptr, srcl, tl,
                 tab + (size_t)l*TROWS*HDIM, xh, agg);
    k_fused23<<<N_NODES/32, 256, 0, stream>>>(agg,
                 cf_w2 + (size_t)l*HDIM*HDIM, cf_b2 + (size_t)l*HDIM,
                 lin_w + (size_t)l*HDIM*HDIM, lin_b + (size_t)l*HDIM, h);
  }
  k_outA  <<<N_NODES/4, 256, 0, stream>>>(h, ow1, ob1, ow2, ob2, nodeval);
  k_outB  <<<NGRAPH, 256, 0, stream>>>(nodeval, batch, (float*)d_out);
}

// Round 3
// 634.254 us; speedup vs baseline: 1.6489x; 1.1391x over previous
//
#include <hip/hip_runtime.h>
#include <math.h>

#define N_NODES 16384
#define N_EDGES 262144
#define HDIM    128
#define NG50    50
#define NLAYER  6
#define NGRAPH  16
#define TROWS   2049
#define RMAXF   4.34f

__device__ __forceinline__ float ssp_f(float x){
  return (x > 20.0f ? x : log1pf(__expf(x))) - 0.6931471805599453f;
}
__device__ __forceinline__ void fma4(float4& c, float a, const float4 b){
  c.x = fmaf(a,b.x,c.x); c.y = fmaf(a,b.y,c.y); c.z = fmaf(a,b.z,c.z); c.w = fmaf(a,b.w,c.w);
}

// ---------------- h = emb[z] ----------------
__global__ __launch_bounds__(256) void k_init_h(const int* __restrict__ z,
    const float* __restrict__ emb, float* __restrict__ h){
  int t = blockIdx.x*256 + threadIdx.x;
  int n = t >> 5, q = t & 31;
  ((float4*)h)[t] = ((const float4*)emb)[(z[n]<<5) + q];
}

// ---------------- edge distances (PBC minimum image), pre-scaled t = r*2048/RMAX ----------------
__global__ __launch_bounds__(256) void k_geom(const int* __restrict__ ei,
    const float* __restrict__ pos, float* __restrict__ tsc){
  int e = blockIdx.x*256 + threadIdx.x;
  if (e >= N_EDGES) return;
  int a = ei[e], b = ei[N_EDGES + e];
  float dx = pos[3*a+0] - pos[3*b+0];
  float dy = pos[3*a+1] - pos[3*b+1];
  float dz = pos[3*a+2] - pos[3*b+2];
  dx -= rintf(dx*0.2f)*5.0f;
  dy -= rintf(dy*0.2f)*5.0f;
  dz -= rintf(dz*0.2f)*5.0f;
  float r = sqrtf(fmaf(dx,dx,fmaf(dy,dy,dz*dz)));
  tsc[e] = r * (2048.0f/RMAXF);
}

// ---------------- per-layer filter tables ----------------
// gaussians computed ONCE per row into LDS (was: 128x redundant per j-thread)
#define TAB_RPB 8
#define TAB_NB  257
__global__ __launch_bounds__(128) void k_tab(const float* __restrict__ w1, const float* __restrict__ b1,
      const float* __restrict__ w2, const float* __restrict__ b2, float* __restrict__ tab){
  __shared__ float w1s[NG50*HDIM];
  __shared__ float sT[TAB_RPB*HDIM];
  __shared__ float eas[TAB_RPB*64];
  int l  = blockIdx.x / TAB_NB;
  int i0 = (blockIdx.x % TAB_NB) * TAB_RPB;
  int j  = threadIdx.x;
  for (int i = j; i < NG50*HDIM; i += 128) w1s[i] = w1[l*NG50*HDIM + i];
  float b1v = b1[l*HDIM + j];
  float b2v = b2[l*HDIM + j];
  const float* w2l = w2 + (size_t)l*HDIM*HDIM;
  float* tabl = tab + (size_t)l*TROWS*HDIM;
  const float STEP = RMAXF/2048.0f;
  const float GS   = 10.0f/49.0f;
  const float GC   = -0.5f/(GS*GS);
  // phase 0: gaussians, one per (row,k)
  for (int w = j; w < TAB_RPB*64; w += 128){
    int rr = w >> 6, k = w & 63;
    if (k < NG50){
      int ri = i0 + rr; if (ri > TROWS-1) ri = TROWS-1;
      float d = ri*STEP - k*GS;
      eas[rr*64 + k] = __expf(GC*d*d);
    }
  }
  __syncthreads();
  for (int rr=0; rr<TAB_RPB; ++rr){
    float acc = 0.f;
    const float* ea = eas + rr*64;
    #pragma unroll 5
    for (int k=0;k<NG50;++k) acc = fmaf(ea[k], w1s[k*HDIM + j], acc);
    sT[rr*HDIM + j] = ssp_f(acc + b1v);
  }
  __syncthreads();
  float o[TAB_RPB];
  #pragma unroll
  for (int rr=0;rr<TAB_RPB;++rr) o[rr]=0.f;
  for (int k=0;k<HDIM;++k){
    float wv = w2l[k*HDIM + j];
    #pragma unroll
    for (int rr=0;rr<TAB_RPB;++rr) o[rr] = fmaf(sT[rr*HDIM + k], wv, o[rr]);
  }
  for (int rr=0;rr<TAB_RPB;++rr){
    int ri = i0 + rr;
    if (ri < TROWS){
      float r = ri*STEP;
      float C = 0.5f*(cosf(r*0.31415926535897931f) + 1.0f);
      tabl[ri*HDIM + j] = (o[rr] + b2v)*C;
    }
  }
}

// ---------------- pack lerp pairs: tabp[l][i][lane] = {tab[i][2m],tab[i][2m+1],tab[i+1][2m],tab[i+1][2m+1]} ----------------
__global__ __launch_bounds__(256) void k_pack(const float* __restrict__ tab, float4* __restrict__ tabp){
  size_t t = (size_t)blockIdx.x*256 + threadIdx.x;   // over 6*2048*64
  int lane = (int)(t & 63);
  size_t row = t >> 6;                                // l*2048 + i
  size_t l = row >> 11, i = row & 2047;
  const float* a = tab + (l*TROWS + i)*HDIM + lane*2;
  float2 av = *(const float2*)a;
  float2 bv = *(const float2*)(a + HDIM);
  tabp[t] = make_float4(av.x, av.y, bv.x, bv.y);
}

// ---------------- CSR build ----------------
__global__ __launch_bounds__(256) void k_hist(const int* __restrict__ ei, int* __restrict__ cursor){
  int e = blockIdx.x*256 + threadIdx.x;
  if (e < N_EDGES) atomicAdd(&cursor[ei[N_EDGES + e]], 1);
}
__global__ __launch_bounds__(1024) void k_scan(int* __restrict__ cursor, int* __restrict__ rowptr){
  __shared__ int sbuf[1024];
  int t = threadIdx.x;
  int base = t*16;
  int d[16]; int s = 0;
  #pragma unroll
  for (int i=0;i<16;++i){ d[i] = cursor[base+i]; s += d[i]; }
  sbuf[t] = s; __syncthreads();
  for (int off=1; off<1024; off<<=1){
    int v = sbuf[t];
    int add = (t >= off) ? sbuf[t-off] : 0;
    __syncthreads();
    sbuf[t] = v + add;
    __syncthreads();
  }
  int run = (t==0) ? 0 : sbuf[t-1];
  #pragma unroll
  for (int i=0;i<16;++i){ rowptr[base+i] = run; cursor[base+i] = run; run += d[i]; }
  if (t==1023) rowptr[N_NODES] = run;
}
__global__ __launch_bounds__(256) void k_fill(const int* __restrict__ ei, const float* __restrict__ tsc,
    int* __restrict__ cursor, int* __restrict__ srcl, float* __restrict__ tl){
  int e = blockIdx.x*256 + threadIdx.x;
  if (e < N_EDGES){
    int c = ei[N_EDGES + e];
    int slot = atomicAdd(&cursor[c], 1);
    srcl[slot] = ei[e];
    tl[slot]   = tsc[e];
  }
}

// ---------------- xh = h @ cf_w1[0] (first layer only) ----------------
__global__ __launch_bounds__(256,2) void k_gemm_xh(const float* __restrict__ A,
    const float* __restrict__ B, float* __restrict__ C){
  int tid = threadIdx.x;
  int m0 = blockIdx.x*32;
  int tc = tid & 31, tr = tid >> 5;
  int j0 = tc*4;
  const float* Arow = A + (size_t)(m0 + tr*4)*HDIM;
  float4 acc0 = make_float4(0,0,0,0), acc1 = acc0, acc2 = acc0, acc3 = acc0;
  #pragma unroll 2
  for (int k=0;k<HDIM;k+=4){
    float4 b0 = *(const float4*)(B + (k+0)*HDIM + j0);
    float4 b1 = *(const float4*)(B + (k+1)*HDIM + j0);
    float4 b2 = *(const float4*)(B + (k+2)*HDIM + j0);
    float4 b3 = *(const float4*)(B + (k+3)*HDIM + j0);
    float4 a0 = *(const float4*)(Arow + 0*HDIM + k);
    float4 a1 = *(const float4*)(Arow + 1*HDIM + k);
    float4 a2 = *(const float4*)(Arow + 2*HDIM + k);
    float4 a3 = *(const float4*)(Arow + 3*HDIM + k);
    fma4(acc0,a0.x,b0); fma4(acc0,a0.y,b1); fma4(acc0,a0.z,b2); fma4(acc0,a0.w,b3);
    fma4(acc1,a1.x,b0); fma4(acc1,a1.y,b1); fma4(acc1,a1.z,b2); fma4(acc1,a1.w,b3);
    fma4(acc2,a2.x,b0); fma4(acc2,a2.y,b1); fma4(acc2,a2.z,b2); fma4(acc2,a2.w,b3);
    fma4(acc3,a3.x,b0); fma4(acc3,a3.y,b1); fma4(acc3,a3.z,b2); fma4(acc3,a3.w,b3);
  }
  float* Crow = C + (size_t)(m0 + tr*4)*HDIM + j0;
  *(float4*)(Crow + 0*HDIM) = acc0;
  *(float4*)(Crow + 1*HDIM) = acc1;
  *(float4*)(Crow + 2*HDIM) = acc2;
  *(float4*)(Crow + 3*HDIM) = acc3;
}

// ---------------- edge aggregation: one wave per dst node, packed table ----------------
__global__ __launch_bounds__(256) void k_agg(const int* __restrict__ rowptr,
    const int* __restrict__ srcl, const float* __restrict__ tl,
    const float4* __restrict__ tabp, const float* __restrict__ xh, float* __restrict__ agg){
  int c = blockIdx.x*4 + (threadIdx.x >> 6);
  int lane = threadIdx.x & 63;
  int beg = rowptr[c], end = rowptr[c+1];
  float ax = 0.f, ay = 0.f;
  for (int k0 = beg; k0 < end; k0 += 64){
    int rem = end - k0;
    int cnt = rem < 64 ? rem : 64;
    int   s_l = 0; float t_l = 0.f;
    if (lane < cnt){ s_l = srcl[k0+lane]; t_l = tl[k0+lane]; }
    int j = 0;
    for (; j+1 < cnt; j += 2){
      int   r0 = __shfl(s_l, j,   64);
      float t0 = __shfl(t_l, j,   64);
      int   r1 = __shfl(s_l, j+1, 64);
      float t1 = __shfl(t_l, j+1, 64);
      int i00 = (int)t0; if (i00 > 2047) i00 = 2047;
      int i01 = (int)t1; if (i01 > 2047) i01 = 2047;
      float f0 = t0 - (float)i00;
      float f1 = t1 - (float)i01;
      float4 p0 = tabp[(size_t)i00*64 + lane];
      float2 x0 = ((const float2*)(xh + (size_t)r0*HDIM))[lane];
      float4 p1 = tabp[(size_t)i01*64 + lane];
      float2 x1 = ((const float2*)(xh + (size_t)r1*HDIM))[lane];
      ax = fmaf(x0.x, fmaf(f0, p0.z-p0.x, p0.x), ax);
      ay = fmaf(x0.y, fmaf(f0, p0.w-p0.y, p0.y), ay);
      ax = fmaf(x1.x, fmaf(f1, p1.z-p1.x, p1.x), ax);
      ay = fmaf(x1.y, fmaf(f1, p1.w-p1.y, p1.y), ay);
    }
    if (j < cnt){
      int   r0 = __shfl(s_l, j, 64);
      float t0 = __shfl(t_l, j, 64);
      int i00 = (int)t0; if (i00 > 2047) i00 = 2047;
      float f0 = t0 - (float)i00;
      float4 p0 = tabp[(size_t)i00*64 + lane];
      float2 x0 = ((const float2*)(xh + (size_t)r0*HDIM))[lane];
      ax = fmaf(x0.x, fmaf(f0, p0.z-p0.x, p0.x), ax);
      ay = fmaf(x0.y, fmaf(f0, p0.w-p0.y, p0.y), ay);
    }
  }
  ((float2*)(agg + (size_t)c*HDIM))[lane] = make_float2(ax, ay);
}

// ---------------- fused interaction: t=ssp(agg@W2+b2); h+=t@WL+bl; xh_next=h@W1n ----------------
template<bool LAST>
__global__ __launch_bounds__(256,2) void k_fused3(const float* __restrict__ Ain,
    const float* __restrict__ W2, const float* __restrict__ B2,
    const float* __restrict__ WL, const float* __restrict__ BL,
    float* __restrict__ Hio, const float* __restrict__ W1n, float* __restrict__ Xout){
  __shared__ float Ss0[32*HDIM];   // t
  __shared__ float Ss1[32*HDIM];   // h'
  int tid = threadIdx.x;
  int m0 = blockIdx.x*32;
  int tc = tid & 31, tr = tid >> 5;
  int j0 = tc*4;
  float4 acc0 = make_float4(0,0,0,0), acc1 = acc0, acc2 = acc0, acc3 = acc0;
  // stage A: agg @ W2
  {
    const float* Arow = Ain + (size_t)(m0 + tr*4)*HDIM;
    #pragma unroll 2
    for (int k=0;k<HDIM;k+=4){
      float4 b0 = *(const float4*)(W2 + (k+0)*HDIM + j0);
      float4 b1 = *(const float4*)(W2 + (k+1)*HDIM + j0);
      float4 b2 = *(const float4*)(W2 + (k+2)*HDIM + j0);
      float4 b3 = *(const float4*)(W2 + (k+3)*HDIM + j0);
      float4 a0 = *(const float4*)(Arow + 0*HDIM + k);
      float4 a1 = *(const float4*)(Arow + 1*HDIM + k);
      float4 a2 = *(const float4*)(Arow + 2*HDIM + k);
      float4 a3 = *(const float4*)(Arow + 3*HDIM + k);
      fma4(acc0,a0.x,b0); fma4(acc0,a0.y,b1); fma4(acc0,a0.z,b2); fma4(acc0,a0.w,b3);
      fma4(acc1,a1.x,b0); fma4(acc1,a1.y,b1); fma4(acc1,a1.z,b2); fma4(acc1,a1.w,b3);
      fma4(acc2,a2.x,b0); fma4(acc2,a2.y,b1); fma4(acc2,a2.z,b2); fma4(acc2,a2.w,b3);
      fma4(acc3,a3.x,b0); fma4(acc3,a3.y,b1); fma4(acc3,a3.z,b2); fma4(acc3,a3.w,b3);
    }
  }
  float4 b2v = *(const float4*)(B2 + j0);
  {
    float* sr = Ss0 + (tr*4)*HDIM + j0;
    float4 v;
    v.x=ssp_f(acc0.x+b2v.x); v.y=ssp_f(acc0.y+b2v.y); v.z=ssp_f(acc0.z+b2v.z); v.w=ssp_f(acc0.w+b2v.w);
    *(float4*)(sr + 0*HDIM) = v;
    v.x=ssp_f(acc1.x+b2v.x); v.y=ssp_f(acc1.y+b2v.y); v.z=ssp_f(acc1.z+b2v.z); v.w=ssp_f(acc1.w+b2v.w);
    *(float4*)(sr + 1*HDIM) = v;
    v.x=ssp_f(acc2.x+b2v.x); v.y=ssp_f(acc2.y+b2v.y); v.z=ssp_f(acc2.z+b2v.z); v.w=ssp_f(acc2.w+b2v.w);
    *(float4*)(sr + 2*HDIM) = v;
    v.x=ssp_f(acc3.x+b2v.x); v.y=ssp_f(acc3.y+b2v.y); v.z=ssp_f(acc3.z+b2v.z); v.w=ssp_f(acc3.w+b2v.w);
    *(float4*)(sr + 3*HDIM) = v;
  }
  __syncthreads();
  // stage B: t @ WL, h' = h + . + bl
  acc0 = make_float4(0,0,0,0); acc1 = acc0; acc2 = acc0; acc3 = acc0;
  {
    const float* Srow = Ss0 + (tr*4)*HDIM;
    #pragma unroll 2
    for (int k=0;k<HDIM;k+=4){
      float4 b0 = *(const float4*)(WL + (k+0)*HDIM + j0);
      float4 b1 = *(const float4*)(WL + (k+1)*HDIM + j0);
      float4 b2 = *(const float4*)(WL + (k+2)*HDIM + j0);
      float4 b3 = *(const float4*)(WL + (k+3)*HDIM + j0);
      float4 a0 = *(const float4*)(Srow + 0*HDIM + k);
      float4 a1 = *(const float4*)(Srow + 1*HDIM + k);
      float4 a2 = *(const float4*)(Srow + 2*HDIM + k);
      float4 a3 = *(const float4*)(Srow + 3*HDIM + k);
      fma4(acc0,a0.x,b0); fma4(acc0,a0.y,b1); fma4(acc0,a0.z,b2); fma4(acc0,a0.w,b3);
      fma4(acc1,a1.x,b0); fma4(acc1,a1.y,b1); fma4(acc1,a1.z,b2); fma4(acc1,a1.w,b3);
      fma4(acc2,a2.x,b0); fma4(acc2,a2.y,b1); fma4(acc2,a2.z,b2); fma4(acc2,a2.w,b3);
      fma4(acc3,a3.x,b0); fma4(acc3,a3.y,b1); fma4(acc3,a3.z,b2); fma4(acc3,a3.w,b3);
    }
  }
  float4 blv = *(const float4*)(BL + j0);
  {
    float* Hrow = Hio + (size_t)(m0 + tr*4)*HDIM + j0;
    float* s1r  = Ss1 + (tr*4)*HDIM + j0;
    float4 hv;
    hv = *(float4*)(Hrow + 0*HDIM);
    hv.x += acc0.x+blv.x; hv.y += acc0.y+blv.y; hv.z += acc0.z+blv.z; hv.w += acc0.w+blv.w;
    *(float4*)(Hrow + 0*HDIM) = hv; if (!LAST) *(float4*)(s1r + 0*HDIM) = hv;
    hv = *(float4*)(Hrow + 1*HDIM);
    hv.x += acc1.x+blv.x; hv.y += acc1.y+blv.y; hv.z += acc1.z+blv.z; hv.w += acc1.w+blv.w;
    *(float4*)(Hrow + 1*HDIM) = hv; if (!LAST) *(float4*)(s1r + 1*HDIM) = hv;
    hv = *(float4*)(Hrow + 2*HDIM);
    hv.x += acc2.x+blv.x; hv.y += acc2.y+blv.y; hv.z += acc2.z+blv.z; hv.w += acc2.w+blv.w;
    *(float4*)(Hrow + 2*HDIM) = hv; if (!LAST) *(float4*)(s1r + 2*HDIM) = hv;
    hv = *(float4*)(Hrow + 3*HDIM);
    hv.x += acc3.x+blv.x; hv.y += acc3.y+blv.y; hv.z += acc3.z+blv.z; hv.w += acc3.w+blv.w;
    *(float4*)(Hrow + 3*HDIM) = hv; if (!LAST) *(float4*)(s1r + 3*HDIM) = hv;
  }
  if (LAST) return;
  __syncthreads();
  // stage C: xh_next = h' @ W1n
  acc0 = make_float4(0,0,0,0); acc1 = acc0; acc2 = acc0; acc3 = acc0;
  {
    const float* Srow = Ss1 + (tr*4)*HDIM;
    #pragma unroll 2
    for (int k=0;k<HDIM;k+=4){
      float4 b0 = *(const float4*)(W1n + (k+0)*HDIM + j0);
      float4 b1 = *(const float4*)(W1n + (k+1)*HDIM + j0);
      float4 b2 = *(const float4*)(W1n + (k+2)*HDIM + j0);
      float4 b3 = *(const float4*)(W1n + (k+3)*HDIM + j0);
      float4 a0 = *(const float4*)(Srow + 0*HDIM + k);
      float4 a1 = *(const float4*)(Srow + 1*HDIM + k);
      float4 a2 = *(const float4*)(Srow + 2*HDIM + k);
      float4 a3 = *(const float4*)(Srow + 3*HDIM + k);
      fma4(acc0,a0.x,b0); fma4(acc0,a0.y,b1); fma4(acc0,a0.z,b2); fma4(acc0,a0.w,b3);
      fma4(acc1,a1.x,b0); fma4(acc1,a1.y,b1); fma4(acc1,a1.z,b2); fma4(acc1,a1.w,b3);
      fma4(acc2,a2.x,b0); fma4(acc2,a2.y,b1); fma4(acc2,a2.z,b2); fma4(acc2,a2.w,b3);
      fma4(acc3,a3.x,b0); fma4(acc3,a3.y,b1); fma4(acc3,a3.z,b2); fma4(acc3,a3.w,b3);
    }
  }
  float* Xrow = Xout + (size_t)(m0 + tr*4)*HDIM + j0;
  *(float4*)(Xrow + 0*HDIM) = acc0;
  *(float4*)(Xrow + 1*HDIM) = acc1;
  *(float4*)(Xrow + 2*HDIM) = acc2;
  *(float4*)(Xrow + 3*HDIM) = acc3;
}

// ---------------- output MLP: per-node scalar (no atomics) ----------------
__global__ __launch_bounds__(256) void k_outA(const float* __restrict__ h, const float* __restrict__ w1,
    const float* __restrict__ b1, const float* __restrict__ w2, const float* __restrict__ b2,
    float* __restrict__ nodeval){
  int node = blockIdx.x*4 + (threadIdx.x >> 6);
  int lane = threadIdx.x & 63;
  float acc = b1[lane];
  const float* hrow = h + (size_t)node*HDIM;
  #pragma unroll 4
  for (int k=0;k<HDIM;++k) acc = fmaf(hrow[k], w1[k*64 + lane], acc);
  float s = ssp_f(acc) * w2[lane];
  for (int off=32; off>0; off>>=1) s += __shfl_down(s, off, 64);
  if (lane == 0) nodeval[node] = s + b2[0];
}

// ---------------- graph readout ----------------
__global__ __launch_bounds__(256) void k_outB(const float* __restrict__ nodeval,
    const int* __restrict__ batch, float* __restrict__ out){
  __shared__ float sred[4];
  int g = blockIdx.x;
  int t = threadIdx.x;
  float s = 0.f;
  for (int n = t; n < N_NODES; n += 256)
    if (batch[n] == g) s += nodeval[n];
  for (int off=32; off>0; off>>=1) s += __shfl_down(s, off, 64);
  if ((t & 63) == 0) sred[t >> 6] = s;
  __syncthreads();
  if (t == 0){
    float tot = sred[0] + sred[1] + sred[2] + sred[3];
    out[g] = 1.0f/(1.0f + __expf(-tot));
  }
}

// ---------------- host ----------------
extern "C" void kernel_launch(void* const* d_in, const int* in_sizes, int n_in,
                              void* d_out, int out_size, void* d_ws, size_t ws_size,
                              hipStream_t stream){
  (void)in_sizes; (void)n_in; (void)out_size;
  const int*   z      = (const int*)  d_in[0];
  const float* pos    = (const float*)d_in[1];
  const int*   ei     = (const int*)  d_in[2];
  const int*   batch  = (const int*)  d_in[3];
  const float* emb    = (const float*)d_in[4];
  const float* mlp_w1 = (const float*)d_in[5];
  const float* mlp_b1 = (const float*)d_in[6];
  const float* mlp_w2 = (const float*)d_in[7];
  const float* mlp_b2 = (const float*)d_in[8];
  const float* cf_w1  = (const float*)d_in[9];
  const float* cf_w2  = (const float*)d_in[10];
  const float* cf_b2  = (const float*)d_in[11];
  const float* lin_w  = (const float*)d_in[12];
  const float* lin_b  = (const float*)d_in[13];
  const float* ow1    = (const float*)d_in[14];
  const float* ob1    = (const float*)d_in[15];
  const float* ow2    = (const float*)d_in[16];
  const float* ob2    = (const float*)d_in[17];

  char* wp = (char*)d_ws;
  size_t used = 0;
  auto alloc = [&](size_t bytes)->char*{
    char* p = wp + used;
    used += (bytes + 1023) & ~(size_t)1023;
    return p;
  };
  float*  tsc     = (float*)alloc((size_t)N_EDGES*4);
  float*  tab     = (float*)alloc((size_t)NLAYER*TROWS*HDIM*4);
  float4* tabp    = (float4*)alloc((size_t)NLAYER*2048*64*16);
  float*  h       = (float*)alloc((size_t)N_NODES*HDIM*4);
  float*  xh      = (float*)alloc((size_t)N_NODES*HDIM*4);
  float*  agg     = (float*)alloc((size_t)N_NODES*HDIM*4);
  int*    rowptr  = (int*)  alloc((size_t)(N_NODES+1)*4);
  int*    cursor  = (int*)  alloc((size_t)N_NODES*4);
  int*    srcl    = (int*)  alloc((size_t)N_EDGES*4);
  float*  tl      = (float*)alloc((size_t)N_EDGES*4);
  float*  nodeval = (float*)alloc((size_t)N_NODES*4);
  if (used > ws_size) return;

  hipMemsetAsync(cursor, 0, (size_t)N_NODES*4, stream);

  k_init_h<<<N_NODES*32/256, 256, 0, stream>>>(z, emb, h);
  k_geom  <<<N_EDGES/256, 256, 0, stream>>>(ei, pos, tsc);
  k_tab   <<<NLAYER*TAB_NB, 128, 0, stream>>>(mlp_w1, mlp_b1, mlp_w2, mlp_b2, tab);
  k_pack  <<<NLAYER*2048*64/256, 256, 0, stream>>>(tab, tabp);
  k_hist  <<<N_EDGES/256, 256, 0, stream>>>(ei, cursor);
  k_scan  <<<1, 1024, 0, stream>>>(cursor, rowptr);
  k_fill  <<<N_EDGES/256, 256, 0, stream>>>(ei, tsc, cursor, srcl, tl);

  k_gemm_xh<<<N_NODES/32, 256, 0, stream>>>(h, cf_w1, xh);
  for (int l=0; l<NLAYER; ++l){
    k_agg<<<N_NODES/4, 256, 0, stream>>>(rowptr, srcl, tl,
                 tabp + (size_t)l*2048*64, xh, agg);
    if (l < NLAYER-1){
      k_fused3<false><<<N_NODES/32, 256, 0, stream>>>(agg,
                 cf_w2 + (size_t)l*HDIM*HDIM, cf_b2 + (size_t)l*HDIM,
                 lin_w + (size_t)l*HDIM*HDIM, lin_b + (size_t)l*HDIM, h,
                 cf_w1 + (size_t)(l+1)*HDIM*HDIM, xh);
    } else {
      k_fused3<true><<<N_NODES/32, 256, 0, stream>>>(agg,
                 cf_w2 + (size_t)l*HDIM*HDIM, cf_b2 + (size_t)l*HDIM,
                 lin_w + (size_t)l*HDIM*HDIM, lin_b + (size_t)l*HDIM, h,
                 nullptr, nullptr);
    }
  }
  k_outA  <<<N_NODES/4, 256, 0, stream>>>(h, ow1, ob1, ow2, ob2, nodeval);
  k_outB  <<<NGRAPH, 256, 0, stream>>>(nodeval, batch, (float*)d_out);
}

// Round 5
// 630.181 us; speedup vs baseline: 1.6596x; 1.0065x over previous
//
#include <hip/hip_runtime.h>
#include <math.h>

#define N_NODES 16384
#define N_EDGES 262144
#define HDIM    128
#define NG50    50
#define NLAYER  6
#define NGRAPH  16
#define TROWS   2049
#define RMAXF   4.34f

__device__ __forceinline__ float ssp_f(float x){
  return (x > 20.0f ? x : log1pf(__expf(x))) - 0.6931471805599453f;
}
__device__ __forceinline__ void fma4(float4& c, float a, const float4 b){
  c.x = fmaf(a,b.x,c.x); c.y = fmaf(a,b.y,c.y); c.z = fmaf(a,b.z,c.z); c.w = fmaf(a,b.w,c.w);
}

// ---------------- h = emb[z] ----------------
__global__ __launch_bounds__(256) void k_init_h(const int* __restrict__ z,
    const float* __restrict__ emb, float* __restrict__ h){
  int t = blockIdx.x*256 + threadIdx.x;
  int n = t >> 5, q = t & 31;
  ((float4*)h)[t] = ((const float4*)emb)[(z[n]<<5) + q];
}

// ---------------- edge distances (PBC minimum image), pre-scaled t = r*2048/RMAX ----------------
__global__ __launch_bounds__(256) void k_geom(const int* __restrict__ ei,
    const float* __restrict__ pos, float* __restrict__ tsc){
  int e = blockIdx.x*256 + threadIdx.x;
  if (e >= N_EDGES) return;
  int a = ei[e], b = ei[N_EDGES + e];
  float dx = pos[3*a+0] - pos[3*b+0];
  float dy = pos[3*a+1] - pos[3*b+1];
  float dz = pos[3*a+2] - pos[3*b+2];
  dx -= rintf(dx*0.2f)*5.0f;
  dy -= rintf(dy*0.2f)*5.0f;
  dz -= rintf(dz*0.2f)*5.0f;
  float r = sqrtf(fmaf(dx,dx,fmaf(dy,dy,dz*dz)));
  tsc[e] = r * (2048.0f/RMAXF);
}

// ---------------- per-layer filter tables ----------------
#define TAB_RPB 16
#define TAB_NB  129   // ceil(2049/16)
__global__ __launch_bounds__(256) void k_tab(const float* __restrict__ w1, const float* __restrict__ b1,
      const float* __restrict__ w2, const float* __restrict__ b2, float* __restrict__ tab){
  __shared__ float eas[TAB_RPB*64];     // 4 KB
  __shared__ float sT[TAB_RPB*HDIM];    // 8 KB
  int l  = blockIdx.x / TAB_NB;
  int i0 = (blockIdx.x % TAB_NB) * TAB_RPB;
  int tid = threadIdx.x;
  int j    = tid & 127;
  int half = tid >> 7;          // 0/1, owns rows half*8 .. half*8+7
  const float* w1l = w1 + (size_t)l*NG50*HDIM;
  const float* w2l = w2 + (size_t)l*HDIM*HDIM;
  float* tabl = tab + (size_t)l*TROWS*HDIM;
  float b1v = b1[l*HDIM + j];
  float b2v = b2[l*HDIM + j];
  const float STEP = RMAXF/2048.0f;
  const float GS   = 10.0f/49.0f;
  const float GC   = -0.5f/(GS*GS);
  // phase 0: gaussians, one per (row,k)
  for (int w = tid; w < TAB_RPB*64; w += 256){
    int rr = w >> 6, k = w & 63;
    if (k < NG50){
      int ri = i0 + rr; if (ri > TROWS-1) ri = TROWS-1;
      float d = ri*STEP - k*GS;
      eas[rr*64 + k] = __expf(GC*d*d);
    }
  }
  __syncthreads();
  // phase 1: sT[rows][j] = ssp(ea @ w1 + b1), 8 rows per thread
  {
    float acc[8];
    #pragma unroll
    for (int r=0;r<8;++r) acc[r]=0.f;
    const float* ea0 = eas + (half*8)*64;
    for (int k=0;k<NG50;++k){
      float wv = w1l[k*HDIM + j];
      #pragma unroll
      for (int r=0;r<8;++r) acc[r] = fmaf(ea0[r*64 + k], wv, acc[r]);
    }
    #pragma unroll
    for (int r=0;r<8;++r) sT[(half*8+r)*HDIM + j] = ssp_f(acc[r] + b1v);
  }
  __syncthreads();
  // phase 2: o = sT @ w2, 8 rows per thread
  float o[8];
  #pragma unroll
  for (int r=0;r<8;++r) o[r]=0.f;
  {
    const float* sT0 = sT + (half*8)*HDIM;
    for (int k=0;k<HDIM;++k){
      float wv = w2l[k*HDIM + j];
      #pragma unroll
      for (int r=0;r<8;++r) o[r] = fmaf(sT0[r*HDIM + k], wv, o[r]);
    }
  }
  // phase 3: cutoff + store
  #pragma unroll
  for (int r=0;r<8;++r){
    int ri = i0 + half*8 + r;
    if (ri < TROWS){
      float rv = ri*STEP;
      float C = 0.5f*(cosf(rv*0.31415926535897931f) + 1.0f);
      tabl[ri*HDIM + j] = (o[r] + b2v)*C;
    }
  }
}

// ---------------- pack lerp pairs ----------------
__global__ __launch_bounds__(256) void k_pack(const float* __restrict__ tab, float4* __restrict__ tabp){
  size_t t = (size_t)blockIdx.x*256 + threadIdx.x;   // over 6*2048*64
  int lane = (int)(t & 63);
  size_t row = t >> 6;                                // l*2048 + i
  size_t l = row >> 11, i = row & 2047;
  const float* a = tab + (l*TROWS + i)*HDIM + lane*2;
  float2 av = *(const float2*)a;
  float2 bv = *(const float2*)(a + HDIM);
  tabp[t] = make_float4(av.x, av.y, bv.x, bv.y);
}

// ---------------- CSR build ----------------
__global__ __launch_bounds__(256) void k_hist(const int* __restrict__ ei, int* __restrict__ cursor){
  int e = blockIdx.x*256 + threadIdx.x;
  if (e < N_EDGES) atomicAdd(&cursor[ei[N_EDGES + e]], 1);
}
__global__ __launch_bounds__(1024) void k_scan(int* __restrict__ cursor, int* __restrict__ rowptr){
  __shared__ int sbuf[1024];
  int t = threadIdx.x;
  int base = t*16;
  int d[16]; int s = 0;
  #pragma unroll
  for (int i=0;i<16;++i){ d[i] = cursor[base+i]; s += d[i]; }
  sbuf[t] = s; __syncthreads();
  for (int off=1; off<1024; off<<=1){
    int v = sbuf[t];
    int add = (t >= off) ? sbuf[t-off] : 0;
    __syncthreads();
    sbuf[t] = v + add;
    __syncthreads();
  }
  int run = (t==0) ? 0 : sbuf[t-1];
  #pragma unroll
  for (int i=0;i<16;++i){ rowptr[base+i] = run; cursor[base+i] = run; run += d[i]; }
  if (t==1023) rowptr[N_NODES] = run;
}
__global__ __launch_bounds__(256) void k_fill(const int* __restrict__ ei, const float* __restrict__ tsc,
    int* __restrict__ cursor, int* __restrict__ srcl, float* __restrict__ tl){
  int e = blockIdx.x*256 + threadIdx.x;
  if (e < N_EDGES){
    int c = ei[N_EDGES + e];
    int slot = atomicAdd(&cursor[c], 1);
    srcl[slot] = ei[e];
    tl[slot]   = tsc[e];
  }
}

// ---------------- xh = h @ cf_w1[0] (first layer only) ----------------
__global__ __launch_bounds__(256,2) void k_gemm_xh(const float* __restrict__ A,
    const float* __restrict__ B, float* __restrict__ C){
  int tid = threadIdx.x;
  int m0 = blockIdx.x*32;
  int tc = tid & 31, tr = tid >> 5;
  int j0 = tc*4;
  const float* Arow = A + (size_t)(m0 + tr*4)*HDIM;
  float4 acc0 = make_float4(0,0,0,0), acc1 = acc0, acc2 = acc0, acc3 = acc0;
  #pragma unroll 2
  for (int k=0;k<HDIM;k+=4){
    float4 b0 = *(const float4*)(B + (k+0)*HDIM + j0);
    float4 b1 = *(const float4*)(B + (k+1)*HDIM + j0);
    float4 b2 = *(const float4*)(B + (k+2)*HDIM + j0);
    float4 b3 = *(const float4*)(B + (k+3)*HDIM + j0);
    float4 a0 = *(const float4*)(Arow + 0*HDIM + k);
    float4 a1 = *(const float4*)(Arow + 1*HDIM + k);
    float4 a2 = *(const float4*)(Arow + 2*HDIM + k);
    float4 a3 = *(const float4*)(Arow + 3*HDIM + k);
    fma4(acc0,a0.x,b0); fma4(acc0,a0.y,b1); fma4(acc0,a0.z,b2); fma4(acc0,a0.w,b3);
    fma4(acc1,a1.x,b0); fma4(acc1,a1.y,b1); fma4(acc1,a1.z,b2); fma4(acc1,a1.w,b3);
    fma4(acc2,a2.x,b0); fma4(acc2,a2.y,b1); fma4(acc2,a2.z,b2); fma4(acc2,a2.w,b3);
    fma4(acc3,a3.x,b0); fma4(acc3,a3.y,b1); fma4(acc3,a3.z,b2); fma4(acc3,a3.w,b3);
  }
  float* Crow = C + (size_t)(m0 + tr*4)*HDIM + j0;
  *(float4*)(Crow + 0*HDIM) = acc0;
  *(float4*)(Crow + 1*HDIM) = acc1;
  *(float4*)(Crow + 2*HDIM) = acc2;
  *(float4*)(Crow + 3*HDIM) = acc3;
}

// ---------------- edge aggregation (unchanged) ----------------
__global__ __launch_bounds__(256) void k_agg(const int* __restrict__ rowptr,
    const int* __restrict__ srcl, const float* __restrict__ tl,
    const float4* __restrict__ tabp, const float* __restrict__ xh, float* __restrict__ agg){
  int c = blockIdx.x*4 + (threadIdx.x >> 6);
  int lane = threadIdx.x & 63;
  int beg = rowptr[c], end = rowptr[c+1];
  float ax = 0.f, ay = 0.f;
  for (int k0 = beg; k0 < end; k0 += 64){
    int rem = end - k0;
    int cnt = rem < 64 ? rem : 64;
    int   s_l = 0; float t_l = 0.f;
    if (lane < cnt){ s_l = srcl[k0+lane]; t_l = tl[k0+lane]; }
    int j = 0;
    for (; j+1 < cnt; j += 2){
      int   r0 = __shfl(s_l, j,   64);
      float t0 = __shfl(t_l, j,   64);
      int   r1 = __shfl(s_l, j+1, 64);
      float t1 = __shfl(t_l, j+1, 64);
      int i00 = (int)t0; if (i00 > 2047) i00 = 2047;
      int i01 = (int)t1; if (i01 > 2047) i01 = 2047;
      float f0 = t0 - (float)i00;
      float f1 = t1 - (float)i01;
      float4 p0 = tabp[(size_t)i00*64 + lane];
      float2 x0 = ((const float2*)(xh + (size_t)r0*HDIM))[lane];
      float4 p1 = tabp[(size_t)i01*64 + lane];
      float2 x1 = ((const float2*)(xh + (size_t)r1*HDIM))[lane];
      ax = fmaf(x0.x, fmaf(f0, p0.z-p0.x, p0.x), ax);
      ay = fmaf(x0.y, fmaf(f0, p0.w-p0.y, p0.y), ay);
      ax = fmaf(x1.x, fmaf(f1, p1.z-p1.x, p1.x), ax);
      ay = fmaf(x1.y, fmaf(f1, p1.w-p1.y, p1.y), ay);
    }
    if (j < cnt){
      int   r0 = __shfl(s_l, j, 64);
      float t0 = __shfl(t_l, j, 64);
      int i00 = (int)t0; if (i00 > 2047) i00 = 2047;
      float f0 = t0 - (float)i00;
      float4 p0 = tabp[(size_t)i00*64 + lane];
      float2 x0 = ((const float2*)(xh + (size_t)r0*HDIM))[lane];
      ax = fmaf(x0.x, fmaf(f0, p0.z-p0.x, p0.x), ax);
      ay = fmaf(x0.y, fmaf(f0, p0.w-p0.y, p0.y), ay);
    }
  }
  ((float2*)(agg + (size_t)c*HDIM))[lane] = make_float2(ax, ay);
}

// ---------------- fused interaction, LDS-staged weights ----------------
// 16 rows/block (1024 blocks, ~4/CU), 256 thr. Bs tile = 32x128 = 1024 float4s,
// filled 4 float4/thread (the R4 bug was filling only 256 of 1024).
#define FR 16   // rows per block
__device__ __forceinline__ void load_chunk(float* Bs, const float* W, int kc, int tid){
  const float4* src = (const float4*)(W + kc*HDIM);
  float4* dst = (float4*)Bs;
  #pragma unroll
  for (int i=0;i<4;++i) dst[tid + i*256] = src[tid + i*256];
}
template<bool LAST>
__global__ __launch_bounds__(256,4) void k_fused3(const float* __restrict__ Ain,
    const float* __restrict__ W2, const float* __restrict__ B2,
    const float* __restrict__ WL, const float* __restrict__ BL,
    float* __restrict__ Hio, const float* __restrict__ W1n, float* __restrict__ Xout){
  __shared__ float Bs[32*HDIM];   // 16 KB weight chunk
  __shared__ float Ss0[FR*HDIM];  // 8 KB t
  __shared__ float Ss1[FR*HDIM];  // 8 KB h'
  int tid = threadIdx.x;
  int m0 = blockIdx.x*FR;
  int tc = tid & 31, tr = tid >> 5;
  int j0 = tc*4;
  int lr0 = tr*2, lr1 = tr*2+1;
  float4 acc0, acc1;

  // ---- stage A: acc = agg @ W2 ----
  acc0 = make_float4(0,0,0,0); acc1 = acc0;
  {
    const float* A0 = Ain + (size_t)(m0 + lr0)*HDIM;
    const float* A1 = Ain + (size_t)(m0 + lr1)*HDIM;
    for (int kc=0; kc<HDIM; kc+=32){
      __syncthreads();
      load_chunk(Bs, W2, kc, tid);
      __syncthreads();
      #pragma unroll
      for (int kk=0; kk<32; kk+=4){
        float4 b0 = *(const float4*)(Bs + (kk+0)*HDIM + j0);
        float4 b1 = *(const float4*)(Bs + (kk+1)*HDIM + j0);
        float4 b2 = *(const float4*)(Bs + (kk+2)*HDIM + j0);
        float4 b3 = *(const float4*)(Bs + (kk+3)*HDIM + j0);
        float4 a0 = *(const float4*)(A0 + kc + kk);
        float4 a1 = *(const float4*)(A1 + kc + kk);
        fma4(acc0,a0.x,b0); fma4(acc0,a0.y,b1); fma4(acc0,a0.z,b2); fma4(acc0,a0.w,b3);
        fma4(acc1,a1.x,b0); fma4(acc1,a1.y,b1); fma4(acc1,a1.z,b2); fma4(acc1,a1.w,b3);
      }
    }
  }
  {
    float4 b2v = *(const float4*)(B2 + j0);
    float4 v;
    v.x=ssp_f(acc0.x+b2v.x); v.y=ssp_f(acc0.y+b2v.y); v.z=ssp_f(acc0.z+b2v.z); v.w=ssp_f(acc0.w+b2v.w);
    *(float4*)(Ss0 + lr0*HDIM + j0) = v;
    v.x=ssp_f(acc1.x+b2v.x); v.y=ssp_f(acc1.y+b2v.y); v.z=ssp_f(acc1.z+b2v.z); v.w=ssp_f(acc1.w+b2v.w);
    *(float4*)(Ss0 + lr1*HDIM + j0) = v;
  }

  // ---- stage B: acc = t @ WL ; h' = h + acc + bl ----
  acc0 = make_float4(0,0,0,0); acc1 = acc0;
  for (int kc=0; kc<HDIM; kc+=32){
    __syncthreads();
    load_chunk(Bs, WL, kc, tid);
    __syncthreads();
    #pragma unroll
    for (int kk=0; kk<32; kk+=4){
      float4 b0 = *(const float4*)(Bs + (kk+0)*HDIM + j0);
      float4 b1 = *(const float4*)(Bs + (kk+1)*HDIM + j0);
      float4 b2 = *(const float4*)(Bs + (kk+2)*HDIM + j0);
      float4 b3 = *(const float4*)(Bs + (kk+3)*HDIM + j0);
      float4 a0 = *(const float4*)(Ss0 + lr0*HDIM + kc + kk);
      float4 a1 = *(const float4*)(Ss0 + lr1*HDIM + kc + kk);
      fma4(acc0,a0.x,b0); fma4(acc0,a0.y,b1); fma4(acc0,a0.z,b2); fma4(acc0,a0.w,b3);
      fma4(acc1,a1.x,b0); fma4(acc1,a1.y,b1); fma4(acc1,a1.z,b2); fma4(acc1,a1.w,b3);
    }
  }
  {
    float4 blv = *(const float4*)(BL + j0);
    float* H0 = Hio + (size_t)(m0 + lr0)*HDIM + j0;
    float* H1 = Hio + (size_t)(m0 + lr1)*HDIM + j0;
    float4 hv;
    hv = *(float4*)H0;
    hv.x += acc0.x+blv.x; hv.y += acc0.y+blv.y; hv.z += acc0.z+blv.z; hv.w += acc0.w+blv.w;
    *(float4*)H0 = hv; if (!LAST) *(float4*)(Ss1 + lr0*HDIM + j0) = hv;
    hv = *(float4*)H1;
    hv.x += acc1.x+blv.x; hv.y += acc1.y+blv.y; hv.z += acc1.z+blv.z; hv.w += acc1.w+blv.w;
    *(float4*)H1 = hv; if (!LAST) *(float4*)(Ss1 + lr1*HDIM + j0) = hv;
  }
  if (LAST) return;

  // ---- stage C: xh_next = h' @ W1n ----
  acc0 = make_float4(0,0,0,0); acc1 = acc0;
  for (int kc=0; kc<HDIM; kc+=32){
    __syncthreads();
    load_chunk(Bs, W1n, kc, tid);
    __syncthreads();
    #pragma unroll
    for (int kk=0; kk<32; kk+=4){
      float4 b0 = *(const float4*)(Bs + (kk+0)*HDIM + j0);
      float4 b1 = *(const float4*)(Bs + (kk+1)*HDIM + j0);
      float4 b2 = *(const float4*)(Bs + (kk+2)*HDIM + j0);
      float4 b3 = *(const float4*)(Bs + (kk+3)*HDIM + j0);
      float4 a0 = *(const float4*)(Ss1 + lr0*HDIM + kc + kk);
      float4 a1 = *(const float4*)(Ss1 + lr1*HDIM + kc + kk);
      fma4(acc0,a0.x,b0); fma4(acc0,a0.y,b1); fma4(acc0,a0.z,b2); fma4(acc0,a0.w,b3);
      fma4(acc1,a1.x,b0); fma4(acc1,a1.y,b1); fma4(acc1,a1.z,b2); fma4(acc1,a1.w,b3);
    }
  }
  *(float4*)(Xout + (size_t)(m0 + lr0)*HDIM + j0) = acc0;
  *(float4*)(Xout + (size_t)(m0 + lr1)*HDIM + j0) = acc1;
}

// ---------------- output MLP: per-node scalar (no atomics) ----------------
__global__ __launch_bounds__(256) void k_outA(const float* __restrict__ h, const float* __restrict__ w1,
    const float* __restrict__ b1, const float* __restrict__ w2, const float* __restrict__ b2,
    float* __restrict__ nodeval){
  int node = blockIdx.x*4 + (threadIdx.x >> 6);
  int lane = threadIdx.x & 63;
  float acc = b1[lane];
  const float* hrow = h + (size_t)node*HDIM;
  #pragma unroll 4
  for (int k=0;k<HDIM;++k) acc = fmaf(hrow[k], w1[k*64 + lane], acc);
  float s = ssp_f(acc) * w2[lane];
  for (int off=32; off>0; off>>=1) s += __shfl_down(s, off, 64);
  if (lane == 0) nodeval[node] = s + b2[0];
}

// ---------------- graph readout ----------------
__global__ __launch_bounds__(256) void k_outB(const float* __restrict__ nodeval,
    const int* __restrict__ batch, float* __restrict__ out){
  __shared__ float sred[4];
  int g = blockIdx.x;
  int t = threadIdx.x;
  float s = 0.f;
  for (int n = t; n < N_NODES; n += 256)
    if (batch[n] == g) s += nodeval[n];
  for (int off=32; off>0; off>>=1) s += __shfl_down(s, off, 64);
  if ((t & 63) == 0) sred[t >> 6] = s;
  __syncthreads();
  if (t == 0){
    float tot = sred[0] + sred[1] + sred[2] + sred[3];
    out[g] = 1.0f/(1.0f + __expf(-tot));
  }
}

// ---------------- host ----------------
extern "C" void kernel_launch(void* const* d_in, const int* in_sizes, int n_in,
                              void* d_out, int out_size, void* d_ws, size_t ws_size,
                              hipStream_t stream){
  (void)in_sizes; (void)n_in; (void)out_size;
  const int*   z      = (const int*)  d_in[0];
  const float* pos    = (const float*)d_in[1];
  const int*   ei     = (const int*)  d_in[2];
  const int*   batch  = (const int*)  d_in[3];
  const float* emb    = (const float*)d_in[4];
  const float* mlp_w1 = (const float*)d_in[5];
  const float* mlp_b1 = (const float*)d_in[6];
  const float* mlp_w2 = (const float*)d_in[7];
  const float* mlp_b2 = (const float*)d_in[8];
  const float* cf_w1  = (const float*)d_in[9];
  const float* cf_w2  = (const float*)d_in[10];
  const float* cf_b2  = (const float*)d_in[11];
  const float* lin_w  = (const float*)d_in[12];
  const float* lin_b  = (const float*)d_in[13];
  const float* ow1    = (const float*)d_in[14];
  const float* ob1    = (const float*)d_in[15];
  const float* ow2    = (const float*)d_in[16];
  const float* ob2    = (const float*)d_in[17];

  char* wp = (char*)d_ws;
  size_t used = 0;
  auto alloc = [&](size_t bytes)->char*{
    char* p = wp + used;
    used += (bytes + 1023) & ~(size_t)1023;
    return p;
  };
  float*  tsc     = (float*)alloc((size_t)N_EDGES*4);
  float*  tab     = (float*)alloc((size_t)NLAYER*TROWS*HDIM*4);
  float4* tabp    = (float4*)alloc((size_t)NLAYER*2048*64*16);
  float*  h       = (float*)alloc((size_t)N_NODES*HDIM*4);
  float*  xh      = (float*)alloc((size_t)N_NODES*HDIM*4);
  float*  agg     = (float*)alloc((size_t)N_NODES*HDIM*4);
  int*    rowptr  = (int*)  alloc((size_t)(N_NODES+1)*4);
  int*    cursor  = (int*)  alloc((size_t)N_NODES*4);
  int*    srcl    = (int*)  alloc((size_t)N_EDGES*4);
  float*  tl      = (float*)alloc((size_t)N_EDGES*4);
  float*  nodeval = (float*)alloc((size_t)N_NODES*4);
  if (used > ws_size) return;

  hipMemsetAsync(cursor, 0, (size_t)N_NODES*4, stream);

  k_init_h<<<N_NODES*32/256, 256, 0, stream>>>(z, emb, h);
  k_geom  <<<N_EDGES/256, 256, 0, stream>>>(ei, pos, tsc);
  k_tab   <<<NLAYER*TAB_NB, 256, 0, stream>>>(mlp_w1, mlp_b1, mlp_w2, mlp_b2, tab);
  k_pack  <<<NLAYER*2048*64/256, 256, 0, stream>>>(tab, tabp);
  k_hist  <<<N_EDGES/256, 256, 0, stream>>>(ei, cursor);
  k_scan  <<<1, 1024, 0, stream>>>(cursor, rowptr);
  k_fill  <<<N_EDGES/256, 256, 0, stream>>>(ei, tsc, cursor, srcl, tl);

  k_gemm_xh<<<N_NODES/32, 256, 0, stream>>>(h, cf_w1, xh);
  for (int l=0; l<NLAYER; ++l){
    k_agg<<<N_NODES/4, 256, 0, stream>>>(rowptr, srcl, tl,
                 tabp + (size_t)l*2048*64, xh, agg);
    if (l < NLAYER-1){
      k_fused3<false><<<N_NODES/FR, 256, 0, stream>>>(agg,
                 cf_w2 + (size_t)l*HDIM*HDIM, cf_b2 + (size_t)l*HDIM,
                 lin_w + (size_t)l*HDIM*HDIM, lin_b + (size_t)l*HDIM, h,
                 cf_w1 + (size_t)(l+1)*HDIM*HDIM, xh);
    } else {
      k_fused3<true><<<N_NODES/FR, 256, 0, stream>>>(agg,
                 cf_w2 + (size_t)l*HDIM*HDIM, cf_b2 + (size_t)l*HDIM,
                 lin_w + (size_t)l*HDIM*HDIM, lin_b + (size_t)l*HDIM, h,
                 nullptr, nullptr);
    }
  }
  k_outA  <<<N_NODES/4, 256, 0, stream>>>(h, ow1, ob1, ow2, ob2, nodeval);
  k_outB  <<<NGRAPH, 256, 0, stream>>>(nodeval, batch, (float*)d_out);
}